// Round 3
// baseline (54.631 us; speedup 1.0000x reference)
//
#include <hip/hip_runtime.h>
#include <hip/hip_bf16.h>

// Fused rule-based LM: fills logits [L,16], attn [L,L], h [L,64] (all fp32).
// One block per row i. All predicates (cond, prev_action) are block-uniform.
// Memory-bound: ~271 MB of stores. Target: pure-store HBM ceiling (~7 TB/s,
// measured on this chip via the harness's fillBufferAligned at 85-88% peak).
// attn stream uses non-temporal stores (never re-read; don't pollute L2).
// NOTE: __builtin_nontemporal_store needs a clang ext_vector type, not HIP's
// float4 class type.

#define VOCAB 16
#define DIM 64
#define NEGV -1e9f

typedef float f32x4 __attribute__((ext_vector_type(4)));

__global__ __launch_bounds__(256) void rulelm_fused(
    const int* __restrict__ ids,
    const float* __restrict__ emb,
    float* __restrict__ logits,
    float* __restrict__ attn,
    float* __restrict__ h,
    int L)
{
    const int i   = blockIdx.x;
    const int tid = threadIdx.x;

    const int id  = ids[i];
    const int idp = (i > 0) ? ids[i - 1] : -1;

    const bool prev_action = (i > 0) && (idp >= 7 && idp <= 9);
    const bool is_pref     = (id == 10) || (id == 11);
    const bool cond        = is_pref && prev_action;

    // ---- small outputs first: logits row (lanes 0-15), h row (lanes 64-79) ----
    if (tid < VOCAB) {
        float val;
        const bool tok_pref = (tid == 10) || (tid == 11);
        if (i == 0) {
            val = NEGV;
        } else if (prev_action) {
            val = tok_pref ? 5.0f : NEGV;
        } else {
            val = tok_pref ? -5.0f : ((tid <= 2) ? NEGV : 1.0f);
        }
        logits[(size_t)i * VOCAB + tid] = val;
    } else if (tid >= 64 && tid < 80) {
        const int q = tid - 64;
        ((float4*)(h + (size_t)i * DIM))[q] =
            ((const float4*)(emb + (size_t)id * DIM))[q];
    }

    // ---- attention row: constant fill + single 0.8 fixup on cond rows ----
    const float each = 0.2f / (float)(L - 1);
    const float base = cond ? each : (1.0f / (float)L);
    const f32x4 fill = {base, base, base, base};

    f32x4* __restrict__ arow = (f32x4*)(attn + (size_t)i * (size_t)L);
    const int nvec  = L >> 2;        // f32x4s per row
    const int iters = nvec >> 8;     // per-thread stores (L % 1024 == 0 path)

    if ((L & 1023) == 0) {
        if (!cond) {
            f32x4* p = arow + tid;
#pragma unroll 8
            for (int t = 0; t < iters; ++t) {
                __builtin_nontemporal_store(fill, p);
                p += 256;
            }
        } else {
            const int ks = (i - 1) >> 2;       // f32x4 index holding 0.8
            const int kl = (i - 1) & 3;        // lane within that f32x4
            f32x4* p = arow + tid;
            int k = tid;
#pragma unroll 8
            for (int t = 0; t < iters; ++t) {
                f32x4 w = fill;
                if (k == ks) w[kl] = 0.8f;
                __builtin_nontemporal_store(w, p);
                p += 256;
                k += 256;
            }
        }
    } else {
        // generic fallback (unused at L=8192)
        const int special = cond ? (i - 1) : -1;
        for (int k = tid; k < nvec; k += 256) {
            f32x4 w = fill;
            const int c0 = k << 2;
            if (special >= c0 && special < c0 + 4) {
                w[special - c0] = 0.8f;
            }
            __builtin_nontemporal_store(w, arow + k);
        }
    }
}

extern "C" void kernel_launch(void* const* d_in, const int* in_sizes, int n_in,
                              void* d_out, int out_size, void* d_ws, size_t ws_size,
                              hipStream_t stream)
{
    const int*   ids = (const int*)d_in[0];
    const float* emb = (const float*)d_in[1];
    const int L = in_sizes[0];  // 8192

    float* out    = (float*)d_out;
    float* logits = out;                                  // L*16
    float* attn   = out + (size_t)L * VOCAB;              // L*L
    float* h      = attn + (size_t)L * (size_t)L;         // L*64

    rulelm_fused<<<L, 256, 0, stream>>>(ids, emb, logits, attn, h, L);
}

// Round 4
// 48.097 us; speedup vs baseline: 1.1358x; 1.1358x over previous
//
#include <hip/hip_runtime.h>
#include <hip/hip_bf16.h>

// Fused rule-based LM: fills logits [L,16], attn [L,L], h [L,64] (all fp32).
// Memory-bound: ~271 MB of plain streaming stores (nt stores measured 15%
// SLOWER on gfx950 — L2 write-combine path is the fast one; reverted).
// 4 rows per block: amortizes the ids-load prologue latency across 4x the
// store work. Grid 2048 x 256 thr = 8 blocks/CU resident.

#define VOCAB 16
#define DIM 64
#define NEGV -1e9f
#define ROWS 4

typedef float f32x4 __attribute__((ext_vector_type(4)));

__global__ __launch_bounds__(256) void rulelm_fused4(
    const int* __restrict__ ids,
    const float* __restrict__ emb,
    float* __restrict__ logits,
    float* __restrict__ attn,
    float* __restrict__ h,
    int L)
{
    const int i0  = blockIdx.x * ROWS;
    const int tid = threadIdx.x;

    // Issue all ids loads up front (overlapped latency).
    int idv[ROWS];
#pragma unroll
    for (int r = 0; r < ROWS; ++r) idv[r] = ids[i0 + r];
    const int idm1 = (i0 > 0) ? ids[i0 - 1] : -1;

#pragma unroll
    for (int r = 0; r < ROWS; ++r) {
        const int i   = i0 + r;
        const int id  = idv[r];
        const int idp = (r == 0) ? idm1 : idv[r - 1];

        const bool prev_action = (i > 0) && (idp >= 7 && idp <= 9);
        const bool is_pref     = (id == 10) || (id == 11);
        const bool cond        = is_pref && prev_action;

        // ---- small outputs: logits row (lanes 0-15), h row (lanes 64-79) ----
        if (tid < VOCAB) {
            float val;
            const bool tok_pref = (tid == 10) || (tid == 11);
            if (i == 0) {
                val = NEGV;
            } else if (prev_action) {
                val = tok_pref ? 5.0f : NEGV;
            } else {
                val = tok_pref ? -5.0f : ((tid <= 2) ? NEGV : 1.0f);
            }
            logits[(size_t)i * VOCAB + tid] = val;
        } else if (tid >= 64 && tid < 80) {
            const int q = tid - 64;
            ((float4*)(h + (size_t)i * DIM))[q] =
                ((const float4*)(emb + (size_t)id * DIM))[q];
        }

        // ---- attention row: constant fill + single 0.8 fixup on cond rows ----
        const float each = 0.2f / (float)(L - 1);
        const float base = cond ? each : (1.0f / (float)L);
        const f32x4 fill = {base, base, base, base};

        f32x4* __restrict__ arow = (f32x4*)(attn + (size_t)i * (size_t)L);
        const int iters = (L >> 2) >> 8;   // f32x4 stores per thread (8 @ L=8192)

        if (!cond) {
            f32x4* p = arow + tid;
#pragma unroll 8
            for (int t = 0; t < iters; ++t) {
                *p = fill;
                p += 256;
            }
        } else {
            const int ks = (i - 1) >> 2;   // f32x4 index holding 0.8
            const int kl = (i - 1) & 3;
            f32x4* p = arow + tid;
            int k = tid;
#pragma unroll 8
            for (int t = 0; t < iters; ++t) {
                f32x4 w = fill;
                if (k == ks) w[kl] = 0.8f;
                *p = w;
                p += 256;
                k += 256;
            }
        }
    }
}

// Generic one-row-per-block fallback (any L).
__global__ __launch_bounds__(256) void rulelm_fused1(
    const int* __restrict__ ids,
    const float* __restrict__ emb,
    float* __restrict__ logits,
    float* __restrict__ attn,
    float* __restrict__ h,
    int L)
{
    const int i   = blockIdx.x;
    const int tid = threadIdx.x;

    const int id  = ids[i];
    const int idp = (i > 0) ? ids[i - 1] : -1;

    const bool prev_action = (i > 0) && (idp >= 7 && idp <= 9);
    const bool is_pref     = (id == 10) || (id == 11);
    const bool cond        = is_pref && prev_action;

    if (tid < VOCAB) {
        float val;
        const bool tok_pref = (tid == 10) || (tid == 11);
        if (i == 0) {
            val = NEGV;
        } else if (prev_action) {
            val = tok_pref ? 5.0f : NEGV;
        } else {
            val = tok_pref ? -5.0f : ((tid <= 2) ? NEGV : 1.0f);
        }
        logits[(size_t)i * VOCAB + tid] = val;
    } else if (tid >= 64 && tid < 80) {
        const int q = tid - 64;
        ((float4*)(h + (size_t)i * DIM))[q] =
            ((const float4*)(emb + (size_t)id * DIM))[q];
    }

    const float each = 0.2f / (float)(L - 1);
    const float base = cond ? each : (1.0f / (float)L);
    const int special = cond ? (i - 1) : -1;

    float* row = attn + (size_t)i * (size_t)L;
    for (int c = tid * 4; c < L; c += 1024) {
        f32x4 w = {base, base, base, base};
        if (special >= c && special < c + 4) w[special - c] = 0.8f;
        *(f32x4*)(row + c) = w;
    }
    // scalar tail (L not multiple of 4) — unused at L=8192
    for (int c = (L & ~3) + tid; c < L; c += 256) {
        row[c] = (c == special) ? 0.8f : base;
    }
}

extern "C" void kernel_launch(void* const* d_in, const int* in_sizes, int n_in,
                              void* d_out, int out_size, void* d_ws, size_t ws_size,
                              hipStream_t stream)
{
    const int*   ids = (const int*)d_in[0];
    const float* emb = (const float*)d_in[1];
    const int L = in_sizes[0];  // 8192

    float* out    = (float*)d_out;
    float* logits = out;                                  // L*16
    float* attn   = out + (size_t)L * VOCAB;              // L*L
    float* h      = attn + (size_t)L * (size_t)L;         // L*64

    if ((L % (ROWS * 1024)) == 0) {
        rulelm_fused4<<<L / ROWS, 256, 0, stream>>>(ids, emb, logits, attn, h, L);
    } else {
        rulelm_fused1<<<L, 256, 0, stream>>>(ids, emb, logits, attn, h, L);
    }
}

// Round 5
// 47.168 us; speedup vs baseline: 1.1582x; 1.0197x over previous
//
#include <hip/hip_runtime.h>
#include <hip/hip_bf16.h>

// Fused rule-based LM: fills logits [L,16], attn [L,L], h [L,64] (all fp32).
// Memory-bound: ~271 MB of plain streaming stores.
// Structure: ONE flat grid-stride sweep per output region (mimicking
// rocclr fillBufferAligned, which sustains 6.9-7.0 TB/s on this buffer) —
// linear write front = max DRAM page locality. Per-wave row metadata is
// scalarized: a 64-lane wave stores 64 consecutive f32x4 (1 KB aligned),
// which never crosses a 32 KB attn row, so row = k>>11 is wave-uniform ->
// readfirstlane + scalar ids loads.
// (nt stores measured 15% SLOWER on gfx950 — write-combine path is the
// fast one. Row-owned-block layouts measured 5.7 TB/s; this targets 6.5+.)

#define VOCAB 16
#define DIM 64
#define NEGV -1e9f

typedef float f32x4 __attribute__((ext_vector_type(4)));

__global__ __launch_bounds__(256) void rulelm_sweep(
    const int* __restrict__ ids,
    const float* __restrict__ emb,
    float* __restrict__ logits,
    float* __restrict__ attn,
    float* __restrict__ h,
    int L)
{
    const int g        = blockIdx.x * 256 + threadIdx.x;
    const int nthreads = gridDim.x * 256;

    const float invL = 1.0f / (float)L;
    const float each = 0.2f / (float)(L - 1);

    // ---- logits: flat (L*16/4) f32x4, value from flat index ----
    const int nlog = (L * VOCAB) >> 2;
    for (int k = g; k < nlog; k += nthreads) {
        const int row = k >> 2;          // 4 chunks per 16-float row
        const int c0  = (k & 3) << 2;    // first token id in this chunk
        const int idp = (row > 0) ? ids[row - 1] : -1;
        const bool pa = (row > 0) && (idp >= 7 && idp <= 9);
        f32x4 w;
#pragma unroll
        for (int j = 0; j < 4; ++j) {
            const int tok = c0 + j;
            const bool tp = (tok == 10) || (tok == 11);
            float v;
            if (row == 0)  v = NEGV;
            else if (pa)   v = tp ? 5.0f : NEGV;
            else           v = tp ? -5.0f : ((tok <= 2) ? NEGV : 1.0f);
            w[j] = v;
        }
        ((f32x4*)logits)[k] = w;
    }

    // ---- h: flat (L*64/4) f32x4 gather from emb (4 KB, cache-resident) ----
    const int nh = (L * DIM) >> 2;
    for (int k = g; k < nh; k += nthreads) {
        const int row = k >> 4;          // 16 chunks per 64-float row
        const int q   = k & 15;
        ((f32x4*)h)[k] = ((const f32x4*)emb)[ids[row] * (DIM >> 2) + q];
    }

    // ---- attn: flat (L*L/4) f32x4 linear sweep, wave-uniform row ----
    const int rsh = 31 - __builtin_clz(L >> 2);    // log2(L/4) = 11 @ L=8192
    const size_t nattn = ((size_t)L * (size_t)L) >> 2;
    f32x4* __restrict__ ap = (f32x4*)attn;

#pragma unroll 4
    for (size_t k = g; k < nattn; k += (size_t)nthreads) {
        // wave-uniform: 64 consecutive aligned chunks stay within one row
        const int row = __builtin_amdgcn_readfirstlane((int)(k >> rsh));
        const int id  = ids[row];
        const int idp = (row > 0) ? ids[row - 1] : -1;
        const bool pa   = (row > 0) && (idp >= 7 && idp <= 9);
        const bool cond = ((id == 10) || (id == 11)) && pa;
        if (!cond) {
            f32x4 w = {invL, invL, invL, invL};
            ap[k] = w;
        } else {
            f32x4 w = {each, each, each, each};
            const size_t ks = ((size_t)row << rsh) + (size_t)((row - 1) >> 2);
            if (k == ks) w[(row - 1) & 3] = 0.8f;
            ap[k] = w;
        }
    }
}

extern "C" void kernel_launch(void* const* d_in, const int* in_sizes, int n_in,
                              void* d_out, int out_size, void* d_ws, size_t ws_size,
                              hipStream_t stream)
{
    const int*   ids = (const int*)d_in[0];
    const float* emb = (const float*)d_in[1];
    const int L = in_sizes[0];  // 8192

    float* out    = (float*)d_out;
    float* logits = out;                                  // L*16
    float* attn   = out + (size_t)L * VOCAB;              // L*L
    float* h      = attn + (size_t)L * (size_t)L;         // L*64

    // 2048 blocks x 256 thr = 524288 threads; attn = exactly 32 iters/thread
    rulelm_sweep<<<2048, 256, 0, stream>>>(ids, emb, logits, attn, h, L);
}